// Round 5
// baseline (321.408 us; speedup 1.0000x reference)
//
#include <hip/hip_runtime.h>

// FDTD rollout, temporally blocked (TS=16 steps/launch), barrier-amortized.
// 256 blocks x 512 threads; block = 32x32 output tile via 64x64 halo region.
// Wave w owns rows [8w, 8w+8); each thread keeps a 16-row register WINDOW
// (rows 8w-4 .. 8w+12) of {cur, pv}. 4 sub-steps run with NO barrier
// (vertical neighbors in window registers, horizontal via DPP lane shifts,
// window validity shrinks 1 row/side/step), then one LDS exchange of the
// 4+4 owned boundary rows (cur & pv) + one __syncthreads.
// Barriers: 3 per launch instead of 16.

#define HH 512
#define WW 512
#define TILE 32
#define TS 16
#define NW 8       // waves per block
#define WIN 16     // window rows per thread
#define EE 4       // sub-steps per exchange period (= halo rows per side)
#define PHC ((float)(2.0 * 3.1415926 * 100.0))

#if __has_builtin(__builtin_amdgcn_update_dpp)
__device__ __forceinline__ float nbrL(float x) {   // value from lane-1
    int i = __builtin_bit_cast(int, x);
    i = __builtin_amdgcn_update_dpp(i, i, 0x138, 0xf, 0xf, false); // wave_shr:1
    return __builtin_bit_cast(float, i);
}
__device__ __forceinline__ float nbrR(float x) {   // value from lane+1
    int i = __builtin_bit_cast(int, x);
    i = __builtin_amdgcn_update_dpp(i, i, 0x130, 0xf, 0xf, false); // wave_shl:1
    return __builtin_bit_cast(float, i);
}
#else
__device__ __forceinline__ float nbrL(float x) { return __shfl_up(x, 1, 64); }
__device__ __forceinline__ float nbrR(float x) { return __shfl_down(x, 1, 64); }
#endif

typedef float (*XchPtr)[2][NW][2][EE][64];  // [buf][arr][wave][side][row][col]

template<bool EDGE>
__device__ __forceinline__ void run_steps(
    float (&cur)[WIN], float (&pv)[WIN], const float (&rr)[WIN],
    const float (&cv)[WIN], unsigned smask, unsigned m0, unsigned m511,
    bool isC0, bool isC511, bool doStore, size_t rowOff,
    float* __restrict__ out, int t0, int nk, int Bn, int w, int lane,
    XchPtr xch)
{
    for (int kb = 0; kb < nk; kb += EE) {
        #pragma unroll
        for (int s = 1; s <= EE; ++s) {
            const int k = kb + s;
            if (k > nk) break;
            const float srcv =
                1500.0f * __sinf(PHC * (float)(Bn + t0 + k + 1) * 1.0e-4f);
            float nc[WIN];
            #pragma unroll
            for (int i = 1; i < WIN - 1; ++i) {
                if (i < s || i >= WIN - s) continue;   // compile-time after unroll
                const float c = cur[i];
                const float u = cur[i - 1];
                const float d = cur[i + 1];
                const float l = nbrL(c);
                const float r = nbrR(c);
                float v = 2.f * c - pv[i] +
                          rr[i] * (((u + d) + (l + r)) - 4.f * c);
                v = ((smask >> i) & 1u) ? srcv : v;
                if (EDGE) {
                    // precedence (last wins): row0 < col0 < col511 < row511
                    if ((m0 >> i) & 1u)   v = c - 1.0e-4f * cv[i] * (c - d);
                    if (isC0)             v = c - 1.0e-4f * cv[i] * (c - r);
                    if (isC511)           v = c - 1.0e-4f * cv[i] * (c - l);
                    if ((m511 >> i) & 1u) v = c - 1.0e-4f * cv[i] * (c - u);
                }
                pv[i] = c;
                nc[i] = v;
            }
            #pragma unroll
            for (int i = 1; i < WIN - 1; ++i) {
                if (i < s || i >= WIN - s) continue;
                cur[i] = nc[i];
            }
            if (doStore) {
                float* op = out + (size_t)(t0 + k - 1) * (size_t)(HH * WW) + rowOff;
                #pragma unroll
                for (int j = 0; j < 8; ++j) op[j * WW] = cur[EE + j];
            }
        }
        if (kb + EE < nk) {
            const int buf = (kb >> 2) & 1;
            #pragma unroll
            for (int j = 0; j < EE; ++j) {
                xch[buf][0][w][0][j][lane] = cur[EE + j];      // owned top 4
                xch[buf][0][w][1][j][lane] = cur[EE + 4 + j];  // owned bottom 4
                xch[buf][1][w][0][j][lane] = pv[EE + j];
                xch[buf][1][w][1][j][lane] = pv[EE + 4 + j];
            }
            __syncthreads();
            if (w > 0) {
                #pragma unroll
                for (int j = 0; j < EE; ++j) {
                    cur[j] = xch[buf][0][w - 1][1][j][lane];
                    pv[j]  = xch[buf][1][w - 1][1][j][lane];
                }
            }
            if (w < NW - 1) {
                #pragma unroll
                for (int j = 0; j < EE; ++j) {
                    cur[12 + j] = xch[buf][0][w + 1][0][j][lane];
                    pv[12 + j]  = xch[buf][1][w + 1][0][j][lane];
                }
            }
        }
    }
}

__global__ __launch_bounds__(512)
void fdtd_win(const float* __restrict__ prevF,
              const float* __restrict__ curF,
              const float* __restrict__ cmap,
              const int* __restrict__ locx,
              const int* __restrict__ locy,
              const int* __restrict__ pb,
              const int* __restrict__ pid2,
              float* __restrict__ out,
              int t0, int nk)
{
    __shared__ float xch[2][2][NW][2][EE][64];

    const int lane = threadIdx.x & 63;
    const int w    = threadIdx.x >> 6;
    const int bx   = blockIdx.x & 15;
    const int by   = blockIdx.x >> 4;
    const int gx0  = bx * TILE - TS;
    const int gy0  = by * TILE - TS;
    const int gc   = gx0 + lane;
    const int B    = w * 8 - EE;        // window base (region row)

    const int lx0 = locx[0], ly0 = locy[0];
    const int lx1 = locx[1], ly1 = locy[1];
    const int lx2 = locx[2], ly2 = locy[2];
    const int Bn  = pb[0] * pid2[0];

    float cur[WIN], pv[WIN], rr[WIN], cv[WIN];
    unsigned smask = 0, m0 = 0, m511 = 0;
    const bool colOK = (gc >= 0) & (gc < WW);

    #pragma unroll
    for (int i = 0; i < WIN; ++i) {
        const int gr = gy0 + B + i;
        float c = 0.f, ce = 0.f, pp = 0.f;
        if (colOK && gr >= 0 && gr < HH) {
            const int gi = gr * WW + gc;
            c = cmap[gi]; ce = curF[gi]; pp = prevF[gi];
        }
        cur[i] = ce; pv[i] = pp; cv[i] = c; rr[i] = 1.0e-8f * c * c;
        if ((gr == lx0 && gc == ly0) || (gr == lx1 && gc == ly1) ||
            (gr == lx2 && gc == ly2)) smask |= (1u << i);
        if (gr == 0)      m0   |= (1u << i);
        if (gr == HH - 1) m511 |= (1u << i);
    }

    const bool edge    = (bx == 0) | (bx == 15) | (by == 0) | (by == 15);
    const bool isC0    = (gc == 0);
    const bool isC511  = (gc == WW - 1);
    const bool doStore = (w >= 2) & (w <= 5) & (lane >= 16) & (lane < 48);
    const size_t rowOff = (size_t)(gy0 + w * 8) * WW + gc;

    if (!edge)
        run_steps<false>(cur, pv, rr, cv, smask, m0, m511, isC0, isC511,
                         doStore, rowOff, out, t0, nk, Bn, w, lane, xch);
    else
        run_steps<true>(cur, pv, rr, cv, smask, m0, m511, isC0, isC511,
                        doStore, rowOff, out, t0, nk, Bn, w, lane, xch);
}

extern "C" void kernel_launch(void* const* d_in, const int* in_sizes, int n_in,
                              void* d_out, int out_size, void* d_ws, size_t ws_size,
                              hipStream_t stream) {
    const float* in_out = (const float*)d_in[0];   // [steps+2, 1, 512, 512]
    const float* cmap   = (const float*)d_in[1];   // [1,1,512,512]
    const int*   locx   = (const int*)d_in[2];
    const int*   locy   = (const int*)d_in[3];
    const int*   pb     = (const int*)d_in[4];     // bsize1
    const int*   pid2   = (const int*)d_in[5];     // id2
    float* out = (float*)d_out;

    const int HW = HH * WW;
    const int steps = out_size / HW;
    const int nblocks = (HH / TILE) * (WW / TILE); // 256

    for (int t0 = 0; t0 < steps; t0 += TS) {
        const int nk = (steps - t0 < TS) ? (steps - t0) : TS;
        const float *prevF, *curF;
        if (t0 == 0) {
            prevF = in_out;
            curF  = in_out + HW;
        } else {
            prevF = out + (size_t)(t0 - 2) * HW;
            curF  = out + (size_t)(t0 - 1) * HW;
        }
        hipLaunchKernelGGL(fdtd_win, dim3(nblocks), dim3(512), 0, stream,
                           prevF, curF, cmap, locx, locy, pb, pid2, out, t0, nk);
    }
}